// Round 1
// baseline (6388.382 us; speedup 1.0000x reference)
//
#include <hip/hip_runtime.h>
#include <math.h>

#define B_ 4
#define T_ 16
#define H_ 64
#define W_ 64
#define CIN 32
#define CO 64
#define NG 256   // 4*CO gate channels

__device__ __forceinline__ float hsig(float z) {
    return fminf(1.f, fmaxf(0.f, 0.2f * z + 0.5f));
}

// Accumulate one conv operand (x-part or h-part) over `nc` input channels.
// s: LDS tile, channel-major [cin][10*10]; wb: weight base for this (ky,kx),
// already offset by this thread's c0; arow: LDS row/col offset for this thread.
__device__ __forceinline__ void accum_part(const float* __restrict__ s, int nc,
                                           const float* __restrict__ wb, int arow,
                                           float (&acc)[4][4][4])
{
#pragma unroll 4
    for (int cin = 0; cin < nc; ++cin) {
        const float* wp = wb + cin * NG;
        float4 w0 = *(const float4*)(wp);
        float4 w1 = *(const float4*)(wp + 64);
        float4 w2 = *(const float4*)(wp + 128);
        float4 w3 = *(const float4*)(wp + 192);
        const float* ap = s + cin * 100 + arow;
        float a0 = ap[0], a1 = ap[1], a2 = ap[2], a3 = ap[3];
#define GATE_(j, aj, g, wg) \
        acc[j][g][0] += aj * wg.x; acc[j][g][1] += aj * wg.y; \
        acc[j][g][2] += aj * wg.z; acc[j][g][3] += aj * wg.w;
#define PIX_(j, aj) GATE_(j, aj, 0, w0) GATE_(j, aj, 1, w1) GATE_(j, aj, 2, w2) GATE_(j, aj, 3, w3)
        PIX_(0, a0) PIX_(1, a1) PIX_(2, a2) PIX_(3, a3)
#undef PIX_
#undef GATE_
    }
}

__global__ __launch_bounds__(256, 1)
void convlstm_step(const float* __restrict__ x,
                   const float* __restrict__ wk,    // (3,3,32,256)
                   const float* __restrict__ wr,    // (3,3,64,256)
                   const float* __restrict__ bias,  // (256,)
                   const float* __restrict__ gamma,
                   const float* __restrict__ beta,
                   const float* __restrict__ mean,
                   const float* __restrict__ var,
                   const float* __restrict__ hin,
                   float* __restrict__ hout,
                   float* __restrict__ cbuf,
                   float* __restrict__ out,
                   int t, int first)
{
    __shared__ float sx[CIN * 100];  // [cin][10*10], halo tile of x_t
    __shared__ float sh[CO * 100];   // [cin][10*10], halo tile of h_{t-1}

    const int tid = threadIdx.x;
    const int b = blockIdx.x >> 6;
    const int tile = blockIdx.x & 63;
    const int oy = (tile >> 3) << 3;
    const int ox = (tile & 7) << 3;

    // ---- stage x tile: 100 positions x 32 ch, as float4 over cin ----
    for (int e = tid; e < 800; e += 256) {
        int q = e & 7, p = e >> 3;
        int iy = p / 10, ix = p - iy * 10;
        int gy = oy + iy - 1, gx = ox + ix - 1;
        float4 v = make_float4(0.f, 0.f, 0.f, 0.f);
        if (gy >= 0 && gy < H_ && gx >= 0 && gx < W_) {
            v = *(const float4*)&x[((((size_t)b * T_ + t) * H_ + gy) * W_ + gx) * CIN + q * 4];
        }
        int base = (q * 4) * 100 + p;
        sx[base] = v.x; sx[base + 100] = v.y; sx[base + 200] = v.z; sx[base + 300] = v.w;
    }
    // ---- stage h tile: 100 positions x 64 ch ----
    if (!first) {
        for (int e = tid; e < 1600; e += 256) {
            int q = e & 15, p = e >> 4;
            int iy = p / 10, ix = p - iy * 10;
            int gy = oy + iy - 1, gx = ox + ix - 1;
            float4 v = make_float4(0.f, 0.f, 0.f, 0.f);
            if (gy >= 0 && gy < H_ && gx >= 0 && gx < W_) {
                v = *(const float4*)&hin[(((size_t)b * H_ + gy) * W_ + gx) * CO + q * 4];
            }
            int base = (q * 4) * 100 + p;
            sh[base] = v.x; sh[base + 100] = v.y; sh[base + 200] = v.z; sh[base + 300] = v.w;
        }
    }
    __syncthreads();

    // thread -> (4 consecutive channels c0..c0+3) x (4 consecutive pixels in a row)
    const int cgrp = tid & 15;
    const int pg = tid >> 4;
    const int c0 = cgrp * 4;
    const int row0 = pg >> 1;          // pixel row within 8x8 tile
    const int colb = (pg & 1) * 4;     // pixel col base within 8x8 tile

    float acc[4][4][4];                // [pixel j][gate][ch]
#pragma unroll
    for (int j = 0; j < 4; ++j)
#pragma unroll
        for (int g = 0; g < 4; ++g)
#pragma unroll
            for (int ch = 0; ch < 4; ++ch) acc[j][g][ch] = 0.f;

#pragma unroll 1
    for (int ky = 0; ky < 3; ++ky) {
#pragma unroll 1
        for (int kx = 0; kx < 3; ++kx) {
            const int arow = (row0 + ky) * 10 + colb + kx;
            accum_part(sx, CIN, wk + (size_t)((ky * 3 + kx) * CIN) * NG + c0, arow, acc);
            if (!first) {
                accum_part(sh, CO, wr + (size_t)((ky * 3 + kx) * CO) * NG + c0, arow, acc);
            }
        }
    }

    // ---- epilogue: gates, state update, BN, stores ----
    const int gy = oy + row0;
#pragma unroll
    for (int j = 0; j < 4; ++j) {
        int gx = ox + colb + j;
        size_t pix = ((size_t)b * H_ + gy) * W_ + gx;
        float cpv[4] = {0.f, 0.f, 0.f, 0.f};
        if (!first) {
            float4 cp = *(const float4*)&cbuf[pix * CO + c0];
            cpv[0] = cp.x; cpv[1] = cp.y; cpv[2] = cp.z; cpv[3] = cp.w;
        }
        float hn[4], cn[4], ov[4];
#pragma unroll
        for (int ch = 0; ch < 4; ++ch) {
            int c = c0 + ch;
            float ig = acc[j][0][ch] + bias[c];
            float fg = acc[j][1][ch] + bias[64 + c];
            float cg = acc[j][2][ch] + bias[128 + c];
            float og = acc[j][3][ch] + bias[192 + c];
            float cv = hsig(fg) * cpv[ch] + hsig(ig) * tanhf(cg);
            float hv = hsig(og) * tanhf(cv);
            cn[ch] = cv; hn[ch] = hv;
            float inv = gamma[c] / sqrtf(var[c] + 1e-3f);
            ov[ch] = hv * inv + (beta[c] - mean[c] * inv);
        }
        *(float4*)&cbuf[pix * CO + c0] = make_float4(cn[0], cn[1], cn[2], cn[3]);
        *(float4*)&hout[pix * CO + c0] = make_float4(hn[0], hn[1], hn[2], hn[3]);
        size_t oidx = ((((size_t)b * T_ + t) * H_ + gy) * W_ + gx) * CO + c0;
        *(float4*)&out[oidx] = make_float4(ov[0], ov[1], ov[2], ov[3]);
    }
}

extern "C" void kernel_launch(void* const* d_in, const int* in_sizes, int n_in,
                              void* d_out, int out_size, void* d_ws, size_t ws_size,
                              hipStream_t stream)
{
    (void)in_sizes; (void)n_in; (void)out_size; (void)ws_size;
    const float* x     = (const float*)d_in[0];
    const float* wk    = (const float*)d_in[1];
    const float* wr    = (const float*)d_in[2];
    const float* bias  = (const float*)d_in[3];
    const float* gamma = (const float*)d_in[4];
    const float* beta  = (const float*)d_in[5];
    const float* mean  = (const float*)d_in[6];
    const float* var   = (const float*)d_in[7];
    float* out = (float*)d_out;

    const size_t plane = (size_t)B_ * H_ * W_ * CO;  // 1,048,576 floats
    float* h0 = (float*)d_ws;
    float* h1 = h0 + plane;
    float* cb = h1 + plane;   // needs 12 MB of d_ws total

    for (int t = 0; t < T_; ++t) {
        const float* hin = (t & 1) ? h0 : h1;  // unused (garbage) at t==0
        float* houtp     = (t & 1) ? h1 : h0;
        convlstm_step<<<256, 256, 0, stream>>>(x, wk, wr, bias, gamma, beta, mean, var,
                                               hin, houtp, cb, out, t, t == 0 ? 1 : 0);
    }
}

// Round 2
// 1523.697 us; speedup vs baseline: 4.1927x; 4.1927x over previous
//
#include <hip/hip_runtime.h>
#include <math.h>

#define B_ 4
#define T_ 16
#define H_ 64
#define W_ 64
#define CIN 32
#define CO 64
#define NG 256   // 4*CO gate channels

__device__ __forceinline__ float hsig(float z) {
    return fminf(1.f, fmaxf(0.f, 0.2f * z + 0.5f));
}

// One conv operand (x-part or h-part).
// s: LDS halo tile, [NC][6][12] (row stride 12 floats, 16B-aligned rows).
// w: weight base (3,3,NC,256) already offset by this lane's channel c.
// wv: wave id == row within the 4-row tile. acc: [px][gate].
template<int NC>
__device__ __forceinline__ void conv_part(const float* __restrict__ s,
                                          const float* __restrict__ w,
                                          int wv, float (&acc)[8][4])
{
#pragma unroll 1
    for (int ky = 0; ky < 3; ++ky) {
        const float* srow_base = s + (wv + ky) * 12;
#pragma unroll 2
        for (int cin = 0; cin < NC; ++cin) {
            const float* srow = srow_base + cin * 72;
            // 10 halo activations for this row: wave-uniform LDS broadcast reads
            float4 A0 = *(const float4*)(srow);
            float4 A1 = *(const float4*)(srow + 4);
            float2 A2 = *(const float2*)(srow + 8);
            float a[10] = {A0.x, A0.y, A0.z, A0.w, A1.x, A1.y, A1.z, A1.w, A2.x, A2.y};
#pragma unroll
            for (int kx = 0; kx < 3; ++kx) {
                const float* wp = w + (size_t)((ky * 3 + kx) * NC + cin) * NG;
                // 4 gate weights, each a dword load coalesced across the 64 lanes
                float w0 = wp[0], w1 = wp[64], w2 = wp[128], w3 = wp[192];
#pragma unroll
                for (int px = 0; px < 8; ++px) {
                    float av = a[px + kx];
                    acc[px][0] += av * w0;
                    acc[px][1] += av * w1;
                    acc[px][2] += av * w2;
                    acc[px][3] += av * w3;
                }
            }
        }
    }
}

__global__ __launch_bounds__(256, 2)
void convlstm_step(const float* __restrict__ x,
                   const float* __restrict__ wk,    // (3,3,32,256)
                   const float* __restrict__ wr,    // (3,3,64,256)
                   const float* __restrict__ bias,  // (256,)
                   const float* __restrict__ gamma,
                   const float* __restrict__ beta,
                   const float* __restrict__ mean,
                   const float* __restrict__ var,
                   const float* __restrict__ hin,
                   float* __restrict__ hout,
                   float* __restrict__ cbuf,
                   float* __restrict__ out,
                   int t, int first)
{
    // halo tiles, channel-major, row stride 12 floats (rows 16B-aligned)
    __shared__ __align__(16) float sx[CIN * 72];  // 10 cols used of 12
    __shared__ __align__(16) float sh[CO * 72];

    const int tid = threadIdx.x;
    const int c = tid & 63;       // lane = output channel
    const int wv = tid >> 6;      // wave = tile row (0..3)

    const int bi = blockIdx.x;
    const int b  = bi >> 7;
    const int ty = (bi >> 3) & 15;
    const int tx = bi & 7;
    const int oy = ty * 4, ox = tx * 8;

    // ---- stage x halo tile: 6 rows x 10 cols x 32 ch ----
    for (int e = tid; e < 480; e += 256) {
        int q = e & 7, p = e >> 3;            // q: cin-quad, p: 0..59
        int row = p / 10, col = p - row * 10;
        int gy = oy - 1 + row, gx = ox - 1 + col;
        float4 v = make_float4(0.f, 0.f, 0.f, 0.f);
        if ((unsigned)gy < (unsigned)H_ && (unsigned)gx < (unsigned)W_)
            v = *(const float4*)&x[((((size_t)b * T_ + t) * H_ + gy) * W_ + gx) * CIN + q * 4];
        int base = row * 12 + col;
        sx[(q * 4 + 0) * 72 + base] = v.x;
        sx[(q * 4 + 1) * 72 + base] = v.y;
        sx[(q * 4 + 2) * 72 + base] = v.z;
        sx[(q * 4 + 3) * 72 + base] = v.w;
    }
    // ---- stage h halo tile: 6 rows x 10 cols x 64 ch ----
    if (!first) {
        for (int e = tid; e < 960; e += 256) {
            int q = e & 15, p = e >> 4;
            int row = p / 10, col = p - row * 10;
            int gy = oy - 1 + row, gx = ox - 1 + col;
            float4 v = make_float4(0.f, 0.f, 0.f, 0.f);
            if ((unsigned)gy < (unsigned)H_ && (unsigned)gx < (unsigned)W_)
                v = *(const float4*)&hin[(((size_t)b * H_ + gy) * W_ + gx) * CO + q * 4];
            int base = row * 12 + col;
            sh[(q * 4 + 0) * 72 + base] = v.x;
            sh[(q * 4 + 1) * 72 + base] = v.y;
            sh[(q * 4 + 2) * 72 + base] = v.z;
            sh[(q * 4 + 3) * 72 + base] = v.w;
        }
    }
    __syncthreads();

    float acc[8][4];
#pragma unroll
    for (int px = 0; px < 8; ++px)
#pragma unroll
        for (int g = 0; g < 4; ++g) acc[px][g] = 0.f;

    conv_part<CIN>(sx, wk + c, wv, acc);
    if (!first) conv_part<CO>(sh, wr + c, wv, acc);

    // ---- epilogue: gates, state update, BN, stores ----
    const float b0 = bias[c], b1 = bias[64 + c], b2 = bias[128 + c], b3 = bias[192 + c];
    const float inv = gamma[c] / sqrtf(var[c] + 1e-3f);
    const float shift = beta[c] - mean[c] * inv;
    const int gy = oy + wv;
#pragma unroll
    for (int px = 0; px < 8; ++px) {
        size_t pix = ((size_t)b * H_ + gy) * W_ + (ox + px);
        float cprev = first ? 0.f : cbuf[pix * CO + c];
        float ig = hsig(acc[px][0] + b0);
        float fg = hsig(acc[px][1] + b1);
        float cg = tanhf(acc[px][2] + b2);
        float og = hsig(acc[px][3] + b3);
        float cv = fg * cprev + ig * cg;
        float hv = og * tanhf(cv);
        cbuf[pix * CO + c] = cv;
        hout[pix * CO + c] = hv;
        out[((((size_t)b * T_ + t) * H_ + gy) * W_ + (ox + px)) * CO + c] = hv * inv + shift;
    }
}

extern "C" void kernel_launch(void* const* d_in, const int* in_sizes, int n_in,
                              void* d_out, int out_size, void* d_ws, size_t ws_size,
                              hipStream_t stream)
{
    (void)in_sizes; (void)n_in; (void)out_size; (void)ws_size;
    const float* x     = (const float*)d_in[0];
    const float* wk    = (const float*)d_in[1];
    const float* wr    = (const float*)d_in[2];
    const float* bias  = (const float*)d_in[3];
    const float* gamma = (const float*)d_in[4];
    const float* beta  = (const float*)d_in[5];
    const float* mean  = (const float*)d_in[6];
    const float* var   = (const float*)d_in[7];
    float* out = (float*)d_out;

    const size_t plane = (size_t)B_ * H_ * W_ * CO;  // 1,048,576 floats
    float* h0 = (float*)d_ws;
    float* h1 = h0 + plane;
    float* cb = h1 + plane;   // 12 MB of d_ws total

    const int nblocks = B_ * (H_ / 4) * (W_ / 8);  // 512
    for (int t = 0; t < T_; ++t) {
        const float* hin = (t & 1) ? h0 : h1;  // unused (garbage) at t==0
        float* houtp     = (t & 1) ? h1 : h0;
        convlstm_step<<<nblocks, 256, 0, stream>>>(x, wk, wr, bias, gamma, beta, mean, var,
                                                   hin, houtp, cb, out, t, t == 0 ? 1 : 0);
    }
}

// Round 3
// 495.781 us; speedup vs baseline: 12.8855x; 3.0733x over previous
//
#include <hip/hip_runtime.h>
#include <math.h>

#define B_ 4
#define T_ 16
#define H_ 64
#define W_ 64
#define CIN 32
#define CO 64
#define NG 256   // 4*CO gate channels

typedef __attribute__((ext_vector_type(8))) short bf16x8;
typedef __attribute__((ext_vector_type(4))) float f32x4;

__device__ __forceinline__ float hsig(float z) {
    return fminf(1.f, fmaxf(0.f, 0.2f * z + 0.5f));
}

__device__ __forceinline__ unsigned short f2bf(float f) {
    union { float f; unsigned u; } v; v.f = f;
    unsigned r = v.u + 0x7FFFu + ((v.u >> 16) & 1u);   // RTNE
    return (unsigned short)(r >> 16);
}

// Transpose+convert weights once per launch:
//   wkT[kpos][n=256][k=32]        from wk (3,3,32,256)
//   wrT[kpos][q=2][n=256][k=32]   from wr (3,3,64,256), q = cin chunk of 32
__global__ void transform_weights(const float* __restrict__ wk,
                                  const float* __restrict__ wr,
                                  unsigned short* __restrict__ wkT,
                                  unsigned short* __restrict__ wrT)
{
    int i = blockIdx.x * 256 + threadIdx.x;
    if (i < 9 * 256 * 32) {
        int k = i & 31, n = (i >> 5) & 255, kpos = i >> 13;
        wkT[i] = f2bf(wk[(kpos * 32 + k) * 256 + n]);
    }
    if (i < 9 * 2 * 256 * 32) {
        int k = i & 31, n = (i >> 5) & 255, q = (i >> 13) & 1, kpos = i >> 14;
        wrT[i] = f2bf(wr[(kpos * 64 + q * 32 + k) * 256 + n]);
    }
}

// One timestep. Block = 64 px (4 rows x 16 cols) x all 256 gate-channels.
// Wave w handles channels ch = w*16 + (lane&15) for all 4 gates (N-tiles g*64+w*16).
__global__ __launch_bounds__(256, 1)
void convlstm_step(const float* __restrict__ x,
                   const unsigned short* __restrict__ wkT,
                   const unsigned short* __restrict__ wrT,
                   const float* __restrict__ bias,
                   const float* __restrict__ gamma,
                   const float* __restrict__ beta,
                   const float* __restrict__ mean,
                   const float* __restrict__ var,
                   const unsigned short* __restrict__ hin,   // bf16 NHWC
                   unsigned short* __restrict__ hout,        // bf16 NHWC
                   float* __restrict__ cbuf,
                   float* __restrict__ out,
                   int t, int first)
{
    // A tiles (halo 6x18), channel-contiguous so A-frag reads are 1KB coalesced
    __shared__ __align__(16) unsigned short sx[6 * 18 * 32];
    __shared__ __align__(16) unsigned short sh[2][6 * 18 * 32];  // h split in cin chunks of 32

    const int tid = threadIdx.x;
    const int w = tid >> 6, lane = tid & 63;
    const int ln = lane & 15, kg = lane >> 4;

    const int bi = blockIdx.x;
    const int b = bi >> 6, tile = bi & 63;
    const int oy = (tile >> 2) * 4;      // 16 row-tiles
    const int ox = (tile & 3) * 16;      // 4 col-tiles

    // ---- stage x halo (fp32 -> bf16): 108 positions x 4 chunks of 8 cin ----
    for (int e = tid; e < 432; e += 256) {
        int c8 = e & 3, p = e >> 2;
        int row = p / 18, col = p - row * 18;
        int gy = oy - 1 + row, gx = ox - 1 + col;
        float4 v0 = make_float4(0.f, 0.f, 0.f, 0.f), v1 = v0;
        if ((unsigned)gy < (unsigned)H_ && (unsigned)gx < (unsigned)W_) {
            const float* p32 = &x[((((size_t)b * T_ + t) * H_ + gy) * W_ + gx) * CIN + c8 * 8];
            v0 = *(const float4*)p32; v1 = *(const float4*)(p32 + 4);
        }
        unsigned short* d = &sx[(row * 18 + col) * 32 + c8 * 8];
        d[0] = f2bf(v0.x); d[1] = f2bf(v0.y); d[2] = f2bf(v0.z); d[3] = f2bf(v0.w);
        d[4] = f2bf(v1.x); d[5] = f2bf(v1.y); d[6] = f2bf(v1.z); d[7] = f2bf(v1.w);
    }
    // ---- stage h halo (bf16 copy): 108 positions x 8 octs of 8 ch ----
    if (!first) {
        for (int e = tid; e < 864; e += 256) {
            int o = e & 7, p = e >> 3;
            int row = p / 18, col = p - row * 18;
            int gy = oy - 1 + row, gx = ox - 1 + col;
            uint4 v = make_uint4(0u, 0u, 0u, 0u);
            if ((unsigned)gy < (unsigned)H_ && (unsigned)gx < (unsigned)W_)
                v = *(const uint4*)&hin[(((size_t)b * H_ + gy) * W_ + gx) * CO + o * 8];
            int q = o >> 2, s = o & 3;
            *(uint4*)&sh[q][(row * 18 + col) * 32 + s * 8] = v;
        }
    }
    __syncthreads();

    f32x4 acc[4][4];   // [gate][row-tile]
#pragma unroll
    for (int g = 0; g < 4; ++g)
#pragma unroll
        for (int r = 0; r < 4; ++r) acc[g][r] = (f32x4){0.f, 0.f, 0.f, 0.f};

    const int nbase = w * 16 + ln;       // lane's channel column within each gate tile

#pragma unroll 1
    for (int ky = 0; ky < 3; ++ky) {
#pragma unroll
        for (int kx = 0; kx < 3; ++kx) {
            const int kpos = ky * 3 + kx;
            bf16x8 a[4];
            // x part: K-chunk of 32
#pragma unroll
            for (int r = 0; r < 4; ++r)
                a[r] = *(const bf16x8*)&sx[((r + ky) * 18 + ln + kx) * 32 + kg * 8];
#pragma unroll
            for (int g = 0; g < 4; ++g) {
                bf16x8 bf = *(const bf16x8*)&wkT[((size_t)kpos * 256 + g * 64 + nbase) * 32 + kg * 8];
#pragma unroll
                for (int r = 0; r < 4; ++r)
                    acc[g][r] = __builtin_amdgcn_mfma_f32_16x16x32_bf16(a[r], bf, acc[g][r], 0, 0, 0);
            }
            if (!first) {
#pragma unroll
                for (int q = 0; q < 2; ++q) {
#pragma unroll
                    for (int r = 0; r < 4; ++r)
                        a[r] = *(const bf16x8*)&sh[q][((r + ky) * 18 + ln + kx) * 32 + kg * 8];
#pragma unroll
                    for (int g = 0; g < 4; ++g) {
                        bf16x8 bf = *(const bf16x8*)&wrT[(((size_t)kpos * 2 + q) * 256 + g * 64 + nbase) * 32 + kg * 8];
#pragma unroll
                        for (int r = 0; r < 4; ++r)
                            acc[g][r] = __builtin_amdgcn_mfma_f32_16x16x32_bf16(a[r], bf, acc[g][r], 0, 0, 0);
                    }
                }
            }
        }
    }

    // ---- epilogue: C-frag row = kg*4+reg (pixel col), col = ln (channel) ----
    const int ch = w * 16 + ln;
    const float bi0 = bias[ch], bi1 = bias[64 + ch], bi2 = bias[128 + ch], bi3 = bias[192 + ch];
    const float inv = gamma[ch] * rsqrtf(var[ch] + 1e-3f);
    const float shift = beta[ch] - mean[ch] * inv;
#pragma unroll
    for (int r = 0; r < 4; ++r) {
        const int gy = oy + r;
#pragma unroll
        for (int reg = 0; reg < 4; ++reg) {
            const int gx = ox + kg * 4 + reg;
            size_t pix = ((size_t)b * H_ + gy) * W_ + gx;
            float cprev = first ? 0.f : cbuf[pix * CO + ch];
            float ig = hsig(acc[0][r][reg] + bi0);
            float fg = hsig(acc[1][r][reg] + bi1);
            float cg = tanhf(acc[2][r][reg] + bi2);
            float og = hsig(acc[3][r][reg] + bi3);
            float cv = fg * cprev + ig * cg;
            float hv = og * tanhf(cv);
            cbuf[pix * CO + ch] = cv;
            hout[pix * CO + ch] = f2bf(hv);
            out[((((size_t)b * T_ + t) * H_ + gy) * W_ + gx) * CO + ch] = hv * inv + shift;
        }
    }
}

extern "C" void kernel_launch(void* const* d_in, const int* in_sizes, int n_in,
                              void* d_out, int out_size, void* d_ws, size_t ws_size,
                              hipStream_t stream)
{
    (void)in_sizes; (void)n_in; (void)out_size; (void)ws_size;
    const float* x     = (const float*)d_in[0];
    const float* wk    = (const float*)d_in[1];
    const float* wr    = (const float*)d_in[2];
    const float* bias  = (const float*)d_in[3];
    const float* gamma = (const float*)d_in[4];
    const float* beta  = (const float*)d_in[5];
    const float* mean  = (const float*)d_in[6];
    const float* var   = (const float*)d_in[7];
    float* out = (float*)d_out;

    const size_t plane = (size_t)B_ * H_ * W_ * CO;           // 1,048,576 elems
    unsigned short* h0 = (unsigned short*)d_ws;               // bf16, 2 MB
    unsigned short* h1 = h0 + plane;                          // bf16, 2 MB
    float* cb = (float*)(h1 + plane);                         // fp32, 4 MB
    unsigned short* wkT = (unsigned short*)(cb + plane);      // 147 KB
    unsigned short* wrT = wkT + 9 * 256 * 32;                 // 295 KB

    transform_weights<<<576, 256, 0, stream>>>(wk, wr, wkT, wrT);

    for (int t = 0; t < T_; ++t) {
        const unsigned short* hin = (t & 1) ? h0 : h1;  // garbage at t==0 (unused)
        unsigned short* houtp     = (t & 1) ? h1 : h0;
        convlstm_step<<<256, 256, 0, stream>>>(x, wkT, wrT, bias, gamma, beta, mean, var,
                                               hin, houtp, cb, out, t, t == 0 ? 1 : 0);
    }
}

// Round 4
// 378.095 us; speedup vs baseline: 16.8962x; 1.3113x over previous
//
#include <hip/hip_runtime.h>
#include <math.h>

#define B_ 4
#define T_ 16
#define H_ 64
#define W_ 64
#define CIN 32
#define CO 64
#define NG 256   // 4*CO gate channels

typedef __attribute__((ext_vector_type(8))) short bf16x8;
typedef __attribute__((ext_vector_type(4))) float f32x4;

__device__ __forceinline__ float hsig(float z) {
    return fminf(1.f, fmaxf(0.f, 0.2f * z + 0.5f));
}

__device__ __forceinline__ unsigned short f2bf(float f) {
    union { float f; unsigned u; } v; v.f = f;
    unsigned r = v.u + 0x7FFFu + ((v.u >> 16) & 1u);   // RTNE
    return (unsigned short)(r >> 16);
}

// Transpose+convert weights once per launch:
//   wkT[kpos][n=256][k=32]        from wk (3,3,32,256)
//   wrT[kpos][q=2][n=256][k=32]   from wr (3,3,64,256), q = cin chunk of 32
__global__ void transform_weights(const float* __restrict__ wk,
                                  const float* __restrict__ wr,
                                  unsigned short* __restrict__ wkT,
                                  unsigned short* __restrict__ wrT)
{
    int i = blockIdx.x * 256 + threadIdx.x;
    if (i < 9 * 256 * 32) {
        int k = i & 31, n = (i >> 5) & 255, kpos = i >> 13;
        wkT[i] = f2bf(wk[(kpos * 32 + k) * 256 + n]);
    }
    if (i < 9 * 2 * 256 * 32) {
        int k = i & 31, n = (i >> 5) & 255, q = (i >> 13) & 1, kpos = i >> 14;
        wrT[i] = f2bf(wr[(kpos * 64 + q * 32 + k) * 256 + n]);
    }
}

// One timestep. Block = 64 px (4 rows x 16 cols) x all 256 gate-channels.
// Wave w handles channels ch = w*16 + (lane&15) for all 4 gates.
// K-loop: fully unrolled 9 kpos, distance-1 register prefetch of B-fragments,
// NO barriers inside the loop so the compiler can emit partial vmcnt waits.
template<bool FIRST>
__global__ __launch_bounds__(256, 1)
void convlstm_step(const float* __restrict__ x,
                   const unsigned short* __restrict__ wkT,
                   const unsigned short* __restrict__ wrT,
                   const float* __restrict__ bias,
                   const float* __restrict__ gamma,
                   const float* __restrict__ beta,
                   const float* __restrict__ mean,
                   const float* __restrict__ var,
                   const unsigned short* __restrict__ hin,   // bf16 NHWC
                   unsigned short* __restrict__ hout,        // bf16 NHWC
                   float* __restrict__ cbuf,
                   float* __restrict__ out,
                   int t)
{
    __shared__ __align__(16) unsigned short sx[6 * 18 * 32];
    __shared__ __align__(16) unsigned short sh[2][6 * 18 * 32];

    const int tid = threadIdx.x;
    const int w = tid >> 6, lane = tid & 63;
    const int ln = lane & 15, kg = lane >> 4;

    const int bi = blockIdx.x;
    const int b = bi >> 6, tile = bi & 63;
    const int oy = (tile >> 2) * 4;      // 16 row-tiles
    const int ox = (tile & 3) * 16;      // 4 col-tiles

    // ---- stage x halo (fp32 -> bf16): 108 positions x 4 chunks of 8 cin ----
    for (int e = tid; e < 432; e += 256) {
        int c8 = e & 3, p = e >> 2;
        int row = p / 18, col = p - row * 18;
        int gy = oy - 1 + row, gx = ox - 1 + col;
        float4 v0 = make_float4(0.f, 0.f, 0.f, 0.f), v1 = v0;
        if ((unsigned)gy < (unsigned)H_ && (unsigned)gx < (unsigned)W_) {
            const float* p32 = &x[((((size_t)b * T_ + t) * H_ + gy) * W_ + gx) * CIN + c8 * 8];
            v0 = *(const float4*)p32; v1 = *(const float4*)(p32 + 4);
        }
        unsigned short* d = &sx[(row * 18 + col) * 32 + c8 * 8];
        d[0] = f2bf(v0.x); d[1] = f2bf(v0.y); d[2] = f2bf(v0.z); d[3] = f2bf(v0.w);
        d[4] = f2bf(v1.x); d[5] = f2bf(v1.y); d[6] = f2bf(v1.z); d[7] = f2bf(v1.w);
    }
    // ---- stage h halo (bf16 copy): 108 positions x 8 octs of 8 ch ----
    if (!FIRST) {
        for (int e = tid; e < 864; e += 256) {
            int o = e & 7, p = e >> 3;
            int row = p / 18, col = p - row * 18;
            int gy = oy - 1 + row, gx = ox - 1 + col;
            uint4 v = make_uint4(0u, 0u, 0u, 0u);
            if ((unsigned)gy < (unsigned)H_ && (unsigned)gx < (unsigned)W_)
                v = *(const uint4*)&hin[(((size_t)b * H_ + gy) * W_ + gx) * CO + o * 8];
            int q = o >> 2, s = o & 3;
            *(uint4*)&sh[q][(row * 18 + col) * 32 + s * 8] = v;
        }
    }
    __syncthreads();

    f32x4 acc[4][4];   // [gate][row-tile]
#pragma unroll
    for (int g = 0; g < 4; ++g)
#pragma unroll
        for (int r = 0; r < 4; ++r) acc[g][r] = (f32x4){0.f, 0.f, 0.f, 0.f};

    const int nbase = w * 16 + ln;
    // lane-constant base pointers into the transformed weights
    const unsigned short* wkp = wkT + (size_t)nbase * 32 + kg * 8;
    const unsigned short* wrp = wrT + (size_t)nbase * 32 + kg * 8;

    bf16x8 bx[4], bh[2][4];
#pragma unroll
    for (int g = 0; g < 4; ++g)
        bx[g] = *(const bf16x8*)(wkp + (size_t)(g * 64) * 32);
    if (!FIRST) {
#pragma unroll
        for (int q = 0; q < 2; ++q)
#pragma unroll
            for (int g = 0; g < 4; ++g)
                bh[q][g] = *(const bf16x8*)(wrp + (size_t)(q * 256 + g * 64) * 32);
    }

#pragma unroll
    for (int kpos = 0; kpos < 9; ++kpos) {
        const int ky = kpos / 3, kx = kpos - ky * 3;   // compile-time after unroll
        // ---- prefetch next kpos's B fragments (independent of current MFMAs) ----
        bf16x8 nbx[4], nbh[2][4];
        if (kpos < 8) {
#pragma unroll
            for (int g = 0; g < 4; ++g)
                nbx[g] = *(const bf16x8*)(wkp + (size_t)((kpos + 1) * 256 + g * 64) * 32);
            if (!FIRST) {
#pragma unroll
                for (int q = 0; q < 2; ++q)
#pragma unroll
                    for (int g = 0; g < 4; ++g)
                        nbh[q][g] = *(const bf16x8*)(wrp + (size_t)(((kpos + 1) * 2 + q) * 256 + g * 64) * 32);
            }
        }
        // ---- compute with current B ----
        bf16x8 a[4];
#pragma unroll
        for (int r = 0; r < 4; ++r)
            a[r] = *(const bf16x8*)&sx[((r + ky) * 18 + ln + kx) * 32 + kg * 8];
#pragma unroll
        for (int g = 0; g < 4; ++g)
#pragma unroll
            for (int r = 0; r < 4; ++r)
                acc[g][r] = __builtin_amdgcn_mfma_f32_16x16x32_bf16(a[r], bx[g], acc[g][r], 0, 0, 0);
        if (!FIRST) {
#pragma unroll
            for (int q = 0; q < 2; ++q) {
#pragma unroll
                for (int r = 0; r < 4; ++r)
                    a[r] = *(const bf16x8*)&sh[q][((r + ky) * 18 + ln + kx) * 32 + kg * 8];
#pragma unroll
                for (int g = 0; g < 4; ++g)
#pragma unroll
                    for (int r = 0; r < 4; ++r)
                        acc[g][r] = __builtin_amdgcn_mfma_f32_16x16x32_bf16(a[r], bh[q][g], acc[g][r], 0, 0, 0);
            }
        }
        // ---- rotate prefetch (dead at kpos==8, elided by unroll) ----
        if (kpos < 8) {
#pragma unroll
            for (int g = 0; g < 4; ++g) bx[g] = nbx[g];
            if (!FIRST) {
#pragma unroll
                for (int q = 0; q < 2; ++q)
#pragma unroll
                    for (int g = 0; g < 4; ++g) bh[q][g] = nbh[q][g];
            }
        }
    }

    // ---- epilogue: batch c-prev loads first (MLP), then gates/BN/stores ----
    const int ch = w * 16 + ln;
    const float bi0 = bias[ch], bi1 = bias[64 + ch], bi2 = bias[128 + ch], bi3 = bias[192 + ch];
    const float inv = gamma[ch] * rsqrtf(var[ch] + 1e-3f);
    const float shift = beta[ch] - mean[ch] * inv;

    float cprev[4][4];
    if (!FIRST) {
#pragma unroll
        for (int r = 0; r < 4; ++r)
#pragma unroll
            for (int reg = 0; reg < 4; ++reg) {
                size_t pix = ((size_t)b * H_ + oy + r) * W_ + (ox + kg * 4 + reg);
                cprev[r][reg] = cbuf[pix * CO + ch];
            }
    } else {
#pragma unroll
        for (int r = 0; r < 4; ++r)
#pragma unroll
            for (int reg = 0; reg < 4; ++reg) cprev[r][reg] = 0.f;
    }

#pragma unroll
    for (int r = 0; r < 4; ++r) {
        const int gy = oy + r;
#pragma unroll
        for (int reg = 0; reg < 4; ++reg) {
            const int gx = ox + kg * 4 + reg;
            size_t pix = ((size_t)b * H_ + gy) * W_ + gx;
            float ig = hsig(acc[0][r][reg] + bi0);
            float fg = hsig(acc[1][r][reg] + bi1);
            float cg = tanhf(acc[2][r][reg] + bi2);
            float og = hsig(acc[3][r][reg] + bi3);
            float cv = fg * cprev[r][reg] + ig * cg;
            float hv = og * tanhf(cv);
            cbuf[pix * CO + ch] = cv;
            hout[pix * CO + ch] = f2bf(hv);
            out[((((size_t)b * T_ + t) * H_ + gy) * W_ + gx) * CO + ch] = hv * inv + shift;
        }
    }
}

extern "C" void kernel_launch(void* const* d_in, const int* in_sizes, int n_in,
                              void* d_out, int out_size, void* d_ws, size_t ws_size,
                              hipStream_t stream)
{
    (void)in_sizes; (void)n_in; (void)out_size; (void)ws_size;
    const float* x     = (const float*)d_in[0];
    const float* wk    = (const float*)d_in[1];
    const float* wr    = (const float*)d_in[2];
    const float* bias  = (const float*)d_in[3];
    const float* gamma = (const float*)d_in[4];
    const float* beta  = (const float*)d_in[5];
    const float* mean  = (const float*)d_in[6];
    const float* var   = (const float*)d_in[7];
    float* out = (float*)d_out;

    const size_t plane = (size_t)B_ * H_ * W_ * CO;           // 1,048,576 elems
    unsigned short* h0 = (unsigned short*)d_ws;               // bf16, 2 MB
    unsigned short* h1 = h0 + plane;                          // bf16, 2 MB
    float* cb = (float*)(h1 + plane);                         // fp32, 4 MB
    unsigned short* wkT = (unsigned short*)(cb + plane);      // 147 KB
    unsigned short* wrT = wkT + 9 * 256 * 32;                 // 295 KB

    transform_weights<<<576, 256, 0, stream>>>(wk, wr, wkT, wrT);

    for (int t = 0; t < T_; ++t) {
        const unsigned short* hin = (t & 1) ? h0 : h1;  // garbage at t==0 (unused)
        unsigned short* houtp     = (t & 1) ? h1 : h0;
        if (t == 0)
            convlstm_step<true><<<256, 256, 0, stream>>>(x, wkT, wrT, bias, gamma, beta, mean, var,
                                                         hin, houtp, cb, out, t);
        else
            convlstm_step<false><<<256, 256, 0, stream>>>(x, wkT, wrT, bias, gamma, beta, mean, var,
                                                          hin, houtp, cb, out, t);
    }
}